// Round 11
// baseline (39.801 us; speedup 1.0000x reference)
//
#include <hip/hip_runtime.h>

// InitMotionParams: out[p,n,i] = sum_j R(p,n)[i,j]*means[p,j] + T(p,n)[i]
// R = cont_6d_to_rmat(sum_k softmax(coefs)[p,k] * motion_rots[k,ts[n],:])
// T = sum_k softmax(coefs)[p,k] * motion_transls[k,ts[n],:]
//
// Round-11 = round-6 (best: 33.8us) with ONE variable changed: BLK 256->1024
// (16 waves/block, 256 gaussians/block, 1563 blocks instead of 6250).
// Rationale (Little's law on round-10 counters): avg resident waves 2560 at
// wave lifetime ~4.4us -> block dispatch rate ~150-185 blocks/us is the
// throughput pin; wall ~= nblocks/rate ~= 34us for all 6250-block variants,
// which is why every intra-block restructure (R5/6/8/9) was neutral. Bigger
// blocks cut dispatch count 4x.
// Proven invariants kept: two-kernel gather->ws (R10 falsified single-kernel
// staging), uniform s_load table via readfirstlane wave-uniform slice id
// (R4 lesson: lane-dependent table addr kills s_load, SGPR 96->32, 3x),
// GPT=1 (R7 remat lesson), no forced min-waves (R2 spill lesson), AoS
// 12-float rows (R8: SoA neutral), per-slice 12B stores (R4/6 evidence:
// complementary wave slices merge in L2, WRITE exactly 37.5MB).
// NO MFMA: Gram-Schmidt amplifies operand error by 1/|a2p| (min ~4e-4 over
// 3.2M samples); bf16 einsum operands would fail by orders of magnitude.
// Softmax: no max-subtraction (inputs ~N(0,1)); 1/sum folded only into the
// translation (Gram-Schmidt is scale-invariant in the weights).

constexpr int KK  = 20;
constexpr int BB  = 8;
constexpr int BLK = 1024;  // 16 waves
constexpr int GPB = 256;   // gaussians per block (4 groups of 64 lanes)
constexpr int ROW = 12;    // floats per (n,k) row in ws: 48 B, 16B-aligned

typedef __attribute__((ext_vector_type(2))) float f32x2;

__global__ void gather_tab(const float* __restrict__ motion_rots,    // (K,F,6)
                           const float* __restrict__ motion_transls, // (K,F,3)
                           const int*   __restrict__ ts,             // (B)
                           float* __restrict__ tab,                  // ws
                           int F)
{
    const int tid = threadIdx.x;
    if (tid < BB * KK) {
        const int n = tid / KK, k = tid % KK;
        const int t = ts[n];
        const float* rp = motion_rots    + ((size_t)k * F + t) * 6;
        const float* tp = motion_transls + ((size_t)k * F + t) * 3;
        float* dst = tab + (n * KK + k) * ROW;
        #pragma unroll
        for (int i = 0; i < 6; ++i) dst[i] = rp[i];
        #pragma unroll
        for (int i = 0; i < 3; ++i) dst[6 + i] = tp[i];
        dst[9] = dst[10] = dst[11] = 0.f;
    }
}

__global__ __launch_bounds__(BLK) void motion_fwd(
    const float* __restrict__ motion_coefs, // (G,K)
    const float* __restrict__ means,        // (G,3)
    const float* __restrict__ tab,          // ws: (B,K,ROW) packed, uniform
    float* __restrict__ out,                // (G,B,3)
    int G)
{
    const int tid = threadIdx.x;
    // wave id 0..15: gaussian-group = wave>>2, slice-quarter = wave&3.
    // Both wave-uniform; readfirstlane makes uniformity PROVABLE so the
    // table path stays s_load (round-4 lesson).
    const int wav  = __builtin_amdgcn_readfirstlane(tid >> 6);
    const int grp  = wav >> 2;          // 0..3: which 64 gaussians
    const int q    = wav & 3;           // 0..3: slices q and q+4
    const int lane = tid & 63;
    const int p    = blockIdx.x * GPB + grp * 64 + lane;  // 32-bit is fine
    const int pc   = p < G ? p : G - 1;                   // clamp for loads

    // softmax weights as k-pairs (f32x2 -> pk-math), unnormalized e^c;
    // 1/sum deferred to the translation only.
    f32x2 w2[KK / 2];
    float invs;
    {
        const float4* crow = reinterpret_cast<const float4*>(motion_coefs + (size_t)pc * KK);
        float s = 0.f;
        #pragma unroll
        for (int u = 0; u < 5; ++u) {
            const float4 v = crow[u];
            const float e0 = __expf(v.x), e1 = __expf(v.y);
            const float e2 = __expf(v.z), e3 = __expf(v.w);
            w2[2*u+0] = (f32x2){e0, e1};
            w2[2*u+1] = (f32x2){e2, e3};
            s += (e0 + e1) + (e2 + e3);
        }
        invs = __builtin_amdgcn_rcpf(s);
    }
    const float mx0 = means[pc*3+0], mx1 = means[pc*3+1], mx2 = means[pc*3+2];

    // one timestep slice: k-reduction (uniform s_load operands) + Gram-Schmidt
    auto do_slice = [&](int sl) {
        const float* tn = tab + (size_t)sl * KK * ROW;  // uniform address

        f32x2 a01 = {0.f, 0.f}, a23 = {0.f, 0.f};
        f32x2 a45 = {0.f, 0.f}, a67 = {0.f, 0.f};
        float a8 = 0.f;

        #pragma unroll
        for (int k = 0; k < KK; ++k) {
            const f32x2 t01 = *reinterpret_cast<const f32x2*>(tn + k*ROW + 0);
            const f32x2 t23 = *reinterpret_cast<const f32x2*>(tn + k*ROW + 2);
            const f32x2 t45 = *reinterpret_cast<const f32x2*>(tn + k*ROW + 4);
            const f32x2 t67 = *reinterpret_cast<const f32x2*>(tn + k*ROW + 6);
            const float t8  = tn[k*ROW + 8];
            const f32x2 wk  = ((k & 1) == 0)
                ? (f32x2){w2[k>>1].x, w2[k>>1].x}
                : (f32x2){w2[k>>1].y, w2[k>>1].y};
            a01 += wk * t01;
            a23 += wk * t23;
            a45 += wk * t45;
            a67 += wk * t67;
            a8   = fmaf(wk.x, t8, a8);
        }

        const float r0 = a01.x, r1 = a01.y, r2 = a23.x;
        const float r3 = a23.y, r4 = a45.x, r5 = a45.y;

        const float n1 = __builtin_amdgcn_sqrtf(fmaf(r0, r0, fmaf(r1, r1, r2*r2)));
        const float i1 = __builtin_amdgcn_rcpf(fmaxf(n1, 1e-12f));
        const float b10 = r0*i1, b11 = r1*i1, b12 = r2*i1;

        const float d  = fmaf(b10, r3, fmaf(b11, r4, b12*r5));
        const float q0 = fmaf(-d, b10, r3);
        const float q1 = fmaf(-d, b11, r4);
        const float q2 = fmaf(-d, b12, r5);
        const float n2 = __builtin_amdgcn_sqrtf(fmaf(q0, q0, fmaf(q1, q1, q2*q2)));
        const float i2 = __builtin_amdgcn_rcpf(fmaxf(n2, 1e-12f));
        const float b20 = q0*i2, b21 = q1*i2, b22 = q2*i2;

        const float b30 = fmaf(b11, b22, -(b12*b21));
        const float b31 = fmaf(b12, b20, -(b10*b22));
        const float b32 = fmaf(b10, b21, -(b11*b20));

        const float u0 = a67.x * invs;   // transl = acc[6..8] * (1/sum)
        const float u1 = a67.y * invs;
        const float u2 = a8    * invs;

        const float o0 = fmaf(b10, mx0, fmaf(b20, mx1, fmaf(b30, mx2, u0)));
        const float o1 = fmaf(b11, mx0, fmaf(b21, mx1, fmaf(b31, mx2, u1)));
        const float o2 = fmaf(b12, mx0, fmaf(b22, mx1, fmaf(b32, mx2, u2)));

        if (p < G) {
            float* op = out + (size_t)p * (BB*3) + sl * 3;
            op[0] = o0; op[1] = o1; op[2] = o2;
        }
    };

    do_slice(q);
    do_slice(q + 4);
}

extern "C" void kernel_launch(void* const* d_in, const int* in_sizes, int n_in,
                              void* d_out, int out_size, void* d_ws, size_t ws_size,
                              hipStream_t stream) {
    const float* motion_rots    = (const float*)d_in[0];
    const float* motion_transls = (const float*)d_in[1];
    const float* motion_coefs   = (const float*)d_in[2];
    const float* means          = (const float*)d_in[3];
    const int*   ts             = (const int*)d_in[4];
    float* out = (float*)d_out;
    float* tab = (float*)d_ws;   // needs BB*KK*ROW*4 = 7680 B

    const int G = in_sizes[3] / 3;            // means is (G,3)
    const int F = in_sizes[0] / (6 * KK);     // motion_rots is (K,F,6)

    gather_tab<<<1, 192, 0, stream>>>(motion_rots, motion_transls, ts, tab, F);

    const int nblk = (G + GPB - 1) / GPB;     // 256 gaussians per block
    motion_fwd<<<nblk, BLK, 0, stream>>>(motion_coefs, means, tab, out, G);
}

// Round 12
// 36.242 us; speedup vs baseline: 1.0982x; 1.0982x over previous
//
#include <hip/hip_runtime.h>

// InitMotionParams: out[p,n,i] = sum_j R(p,n)[i,j]*means[p,j] + T(p,n)[i]
// R = cont_6d_to_rmat(sum_k softmax(coefs)[p,k] * motion_rots[k,ts[n],:])
// T = sum_k softmax(coefs)[p,k] * motion_transls[k,ts[n],:]
//
// Round-12 = round-6 body (best: 33.8us) made PERSISTENT: grid capped at
// 2048 blocks (8/CU), grid-stride loop over gaussian-groups. Rationale: 11
// rounds of ledger show block count/size/layout/sharing all pinned at
// 34-36us with Occupancy ~32%, VALUBusy ~36%, HBM ~16% -- machine never
// fills. The untried axis is wave LIFETIME: short waves (~2 slices) pay a
// cold front-end (coef VMEM + 20-exp chain) per wave and churn the CP. A
// barrier-free grid-stride loop makes waves ~3x longer; iteration i+1's
// coef VMEM overlaps iteration i's einsum/GS; launch churn /3.
// Proven invariants kept: two-kernel gather->ws (R10 falsified LDS staging),
// uniform s_load table via readfirstlane wave-uniform slice id (R4: lane-
// dependent addr kills s_load, SGPR 96->32, 3x), GPT=1 per iteration (R7
// remat lesson), no forced min-waves (R2 spill lesson), AoS 12-float rows
// (R8: SoA neutral), per-slice 12B stores (R4/6: complementary wave slices
// merge in L2, WRITE exactly 37.5MB), BLK=256 (R9/R11: bigger neutral/worse).
// NO MFMA: Gram-Schmidt amplifies operand error by 1/|a2p| (min ~4e-4 over
// 3.2M samples); bf16 einsum operands would fail by orders of magnitude.
// Softmax: no max-subtraction (inputs ~N(0,1)); 1/sum folded only into the
// translation (Gram-Schmidt is scale-invariant in the weights).

constexpr int KK   = 20;
constexpr int BB   = 8;
constexpr int BLK  = 256;
constexpr int GPB  = 64;    // gaussians per block-iteration (1/lane, 4 waves)
constexpr int ROW  = 12;    // floats per (n,k) row in ws: 48 B, 16B-aligned
constexpr int PGRID = 2048; // persistent grid: 8 blocks/CU x 256 CUs

typedef __attribute__((ext_vector_type(2))) float f32x2;

__global__ void gather_tab(const float* __restrict__ motion_rots,    // (K,F,6)
                           const float* __restrict__ motion_transls, // (K,F,3)
                           const int*   __restrict__ ts,             // (B)
                           float* __restrict__ tab,                  // ws
                           int F)
{
    const int tid = threadIdx.x;
    if (tid < BB * KK) {
        const int n = tid / KK, k = tid % KK;
        const int t = ts[n];
        const float* rp = motion_rots    + ((size_t)k * F + t) * 6;
        const float* tp = motion_transls + ((size_t)k * F + t) * 3;
        float* dst = tab + (n * KK + k) * ROW;
        #pragma unroll
        for (int i = 0; i < 6; ++i) dst[i] = rp[i];
        #pragma unroll
        for (int i = 0; i < 3; ++i) dst[6 + i] = tp[i];
        dst[9] = dst[10] = dst[11] = 0.f;
    }
}

__global__ __launch_bounds__(BLK) void motion_fwd(
    const float* __restrict__ motion_coefs, // (G,K)
    const float* __restrict__ means,        // (G,3)
    const float* __restrict__ tab,          // ws: (B,K,ROW) packed, uniform
    float* __restrict__ out,                // (G,B,3)
    int G, int nvirt)
{
    const int tid  = threadIdx.x;
    // wave-uniform slice quarter, provably uniform (s_load guarantee):
    const int q    = __builtin_amdgcn_readfirstlane(tid >> 6);  // wave 0..3
    const int lane = tid & 63;

    for (int vb = blockIdx.x; vb < nvirt; vb += PGRID) {
        const int p  = vb * GPB + lane;        // 32-bit: G*24 < 2^31
        const int pc = p < G ? p : G - 1;      // clamp for loads

        // softmax weights, unnormalized e^c; 1/sum deferred to translation
        f32x2 w2[KK / 2];
        float invs;
        {
            const float4* crow =
                reinterpret_cast<const float4*>(motion_coefs + (size_t)pc * KK);
            float s = 0.f;
            #pragma unroll
            for (int u = 0; u < 5; ++u) {
                const float4 v = crow[u];
                const float e0 = __expf(v.x), e1 = __expf(v.y);
                const float e2 = __expf(v.z), e3 = __expf(v.w);
                w2[2*u+0] = (f32x2){e0, e1};
                w2[2*u+1] = (f32x2){e2, e3};
                s += (e0 + e1) + (e2 + e3);
            }
            invs = __builtin_amdgcn_rcpf(s);
        }
        const float mx0 = means[pc*3+0], mx1 = means[pc*3+1], mx2 = means[pc*3+2];

        // one slice: k-reduction (uniform s_load operands) + Gram-Schmidt
        auto do_slice = [&](int sl) {
            const float* tn = tab + (size_t)sl * KK * ROW;  // uniform address

            f32x2 a01 = {0.f, 0.f}, a23 = {0.f, 0.f};
            f32x2 a45 = {0.f, 0.f}, a67 = {0.f, 0.f};
            float a8 = 0.f;

            #pragma unroll
            for (int k = 0; k < KK; ++k) {
                const f32x2 t01 = *reinterpret_cast<const f32x2*>(tn + k*ROW + 0);
                const f32x2 t23 = *reinterpret_cast<const f32x2*>(tn + k*ROW + 2);
                const f32x2 t45 = *reinterpret_cast<const f32x2*>(tn + k*ROW + 4);
                const f32x2 t67 = *reinterpret_cast<const f32x2*>(tn + k*ROW + 6);
                const float t8  = tn[k*ROW + 8];
                const f32x2 wk  = ((k & 1) == 0)
                    ? (f32x2){w2[k>>1].x, w2[k>>1].x}
                    : (f32x2){w2[k>>1].y, w2[k>>1].y};
                a01 += wk * t01;
                a23 += wk * t23;
                a45 += wk * t45;
                a67 += wk * t67;
                a8   = fmaf(wk.x, t8, a8);
            }

            const float r0 = a01.x, r1 = a01.y, r2 = a23.x;
            const float r3 = a23.y, r4 = a45.x, r5 = a45.y;

            const float n1 = __builtin_amdgcn_sqrtf(fmaf(r0, r0, fmaf(r1, r1, r2*r2)));
            const float i1 = __builtin_amdgcn_rcpf(fmaxf(n1, 1e-12f));
            const float b10 = r0*i1, b11 = r1*i1, b12 = r2*i1;

            const float d  = fmaf(b10, r3, fmaf(b11, r4, b12*r5));
            const float q0 = fmaf(-d, b10, r3);
            const float q1 = fmaf(-d, b11, r4);
            const float q2 = fmaf(-d, b12, r5);
            const float n2 = __builtin_amdgcn_sqrtf(fmaf(q0, q0, fmaf(q1, q1, q2*q2)));
            const float i2 = __builtin_amdgcn_rcpf(fmaxf(n2, 1e-12f));
            const float b20 = q0*i2, b21 = q1*i2, b22 = q2*i2;

            const float b30 = fmaf(b11, b22, -(b12*b21));
            const float b31 = fmaf(b12, b20, -(b10*b22));
            const float b32 = fmaf(b10, b21, -(b11*b20));

            const float u0 = a67.x * invs;   // transl = acc[6..8] * (1/sum)
            const float u1 = a67.y * invs;
            const float u2 = a8    * invs;

            const float o0 = fmaf(b10, mx0, fmaf(b20, mx1, fmaf(b30, mx2, u0)));
            const float o1 = fmaf(b11, mx0, fmaf(b21, mx1, fmaf(b31, mx2, u1)));
            const float o2 = fmaf(b12, mx0, fmaf(b22, mx1, fmaf(b32, mx2, u2)));

            if (p < G) {
                float* op = out + (size_t)p * (BB*3) + sl * 3;
                op[0] = o0; op[1] = o1; op[2] = o2;
            }
        };

        do_slice(q);
        do_slice(q + 4);
    }
}

extern "C" void kernel_launch(void* const* d_in, const int* in_sizes, int n_in,
                              void* d_out, int out_size, void* d_ws, size_t ws_size,
                              hipStream_t stream) {
    const float* motion_rots    = (const float*)d_in[0];
    const float* motion_transls = (const float*)d_in[1];
    const float* motion_coefs   = (const float*)d_in[2];
    const float* means          = (const float*)d_in[3];
    const int*   ts             = (const int*)d_in[4];
    float* out = (float*)d_out;
    float* tab = (float*)d_ws;   // needs BB*KK*ROW*4 = 7680 B

    const int G = in_sizes[3] / 3;            // means is (G,3)
    const int F = in_sizes[0] / (6 * KK);     // motion_rots is (K,F,6)

    gather_tab<<<1, 192, 0, stream>>>(motion_rots, motion_transls, ts, tab, F);

    const int nvirt = (G + GPB - 1) / GPB;    // 6250 gaussian-groups
    const int nblk  = nvirt < PGRID ? nvirt : PGRID;
    motion_fwd<<<nblk, BLK, 0, stream>>>(motion_coefs, means, tab, out, G, nvirt);
}

// Round 13
// 34.788 us; speedup vs baseline: 1.1441x; 1.0418x over previous
//
#include <hip/hip_runtime.h>

// InitMotionParams: out[p,n,i] = sum_j R(p,n)[i,j]*means[p,j] + T(p,n)[i]
// R = cont_6d_to_rmat(sum_k softmax(coefs)[p,k] * motion_rots[k,ts[n],:])
// T = sum_k softmax(coefs)[p,k] * motion_transls[k,ts[n],:]
//
// Round-13: two-constraint crossover model from the 12-round ledger:
//  (1) CP dispatches ~150-200 blocks/us -> 6250-block grids floor at ~31us
//      no matter the per-block work (R6/8/9 intra-block edits all neutral);
//  (2) fewer/fatter blocks shift the pin to the per-wave SERIAL chain
//      (coef VMEM -> exp -> per-slice {s_load drain -> FMA -> ~300cy
//      dependent Gram-Schmidt} x slices): R3/R5.
// Fix both at once: SLICE-LEVEL ILP. Each wave owns 4 slices processed as
// 2 rounds of 2 CONCURRENT slices (independent acc sets + s_load streams +
// GS chains; compiler interleaves) -> per-wave critical path ~= 2 chains,
// not 4, while GPB=128 cuts the grid to 3125 blocks (CP floor ~17-21us).
// Slices 0..3 of a gaussian are 48 contiguous bytes -> 3x float4 dense
// stores (R4/5-proven shape, WRITE exactly 37.5MB). Softmax redundancy
// 4x -> 2x.
// Remat guard (R7 lesson): ONE gaussian per lane, ONE w2 set, named-scalar
// accumulators/outputs. Proven invariants: two-kernel gather->ws (R10),
// uniform s_load via readfirstlane wave-uniform ids (R4), no forced
// min-waves (R2), AoS 12-float rows (R8), BLK=256 (R9/R11).
// NO MFMA: Gram-Schmidt amplifies operand error by 1/|a2p| (min ~4e-4);
// bf16 operands would fail by orders of magnitude.
// Softmax: no max-subtraction (inputs ~N(0,1)); 1/sum folded only into the
// translation (Gram-Schmidt is scale-invariant in the weights).

constexpr int KK  = 20;
constexpr int BB  = 8;
constexpr int BLK = 256;
constexpr int GPB = 128;   // 2 gaussian-halves x 64 lanes; 4 slices per wave
constexpr int ROW = 12;    // floats per (n,k) row in ws: 48 B, 16B-aligned

typedef __attribute__((ext_vector_type(2))) float f32x2;

__global__ void gather_tab(const float* __restrict__ motion_rots,    // (K,F,6)
                           const float* __restrict__ motion_transls, // (K,F,3)
                           const int*   __restrict__ ts,             // (B)
                           float* __restrict__ tab,                  // ws
                           int F)
{
    const int tid = threadIdx.x;
    if (tid < BB * KK) {
        const int n = tid / KK, k = tid % KK;
        const int t = ts[n];
        const float* rp = motion_rots    + ((size_t)k * F + t) * 6;
        const float* tp = motion_transls + ((size_t)k * F + t) * 3;
        float* dst = tab + (n * KK + k) * ROW;
        #pragma unroll
        for (int i = 0; i < 6; ++i) dst[i] = rp[i];
        #pragma unroll
        for (int i = 0; i < 3; ++i) dst[6 + i] = tp[i];
        dst[9] = dst[10] = dst[11] = 0.f;
    }
}

__global__ __launch_bounds__(BLK) void motion_fwd(
    const float* __restrict__ motion_coefs, // (G,K)
    const float* __restrict__ means,        // (G,3)
    const float* __restrict__ tab,          // ws: (B,K,ROW) packed, uniform
    float* __restrict__ out,                // (G,B,3)
    int G)
{
    const int tid  = threadIdx.x;
    // wave-uniform ids, provably uniform (s_load guarantee, R4 lesson):
    const int wav  = __builtin_amdgcn_readfirstlane(tid >> 6);  // 0..3
    const int half = wav & 1;    // which 64 gaussians of the block's 128
    const int q4   = wav >> 1;   // slice half: 0 -> slices 0..3, 1 -> 4..7
    const int lane = tid & 63;
    const int p    = blockIdx.x * GPB + half * 64 + lane;
    const int pc   = p < G ? p : G - 1;     // clamp for loads

    // softmax weights as k-pairs, unnormalized e^c; 1/sum deferred
    f32x2 w2[KK / 2];
    float invs;
    {
        const float4* crow =
            reinterpret_cast<const float4*>(motion_coefs + (size_t)pc * KK);
        float s = 0.f;
        #pragma unroll
        for (int u = 0; u < 5; ++u) {
            const float4 v = crow[u];
            const float e0 = __expf(v.x), e1 = __expf(v.y);
            const float e2 = __expf(v.z), e3 = __expf(v.w);
            w2[2*u+0] = (f32x2){e0, e1};
            w2[2*u+1] = (f32x2){e2, e3};
            s += (e0 + e1) + (e2 + e3);
        }
        invs = __builtin_amdgcn_rcpf(s);
    }
    const float mx0 = means[pc*3+0], mx1 = means[pc*3+1], mx2 = means[pc*3+2];

    // Gram-Schmidt + transform for one reduced 9-vector
    auto finish = [&](float r0, float r1, float r2, float r3, float r4,
                      float r5, float r6, float r7, float r8,
                      float& O0, float& O1, float& O2) {
        const float n1 = __builtin_amdgcn_sqrtf(fmaf(r0, r0, fmaf(r1, r1, r2*r2)));
        const float i1 = __builtin_amdgcn_rcpf(fmaxf(n1, 1e-12f));
        const float b10 = r0*i1, b11 = r1*i1, b12 = r2*i1;

        const float d  = fmaf(b10, r3, fmaf(b11, r4, b12*r5));
        const float q0 = fmaf(-d, b10, r3);
        const float q1 = fmaf(-d, b11, r4);
        const float q2 = fmaf(-d, b12, r5);
        const float n2 = __builtin_amdgcn_sqrtf(fmaf(q0, q0, fmaf(q1, q1, q2*q2)));
        const float i2 = __builtin_amdgcn_rcpf(fmaxf(n2, 1e-12f));
        const float b20 = q0*i2, b21 = q1*i2, b22 = q2*i2;

        const float b30 = fmaf(b11, b22, -(b12*b21));
        const float b31 = fmaf(b12, b20, -(b10*b22));
        const float b32 = fmaf(b10, b21, -(b11*b20));

        const float u0 = r6 * invs;   // transl = acc[6..8] * (1/sum)
        const float u1 = r7 * invs;
        const float u2 = r8 * invs;

        O0 = fmaf(b10, mx0, fmaf(b20, mx1, fmaf(b30, mx2, u0)));
        O1 = fmaf(b11, mx0, fmaf(b21, mx1, fmaf(b31, mx2, u1)));
        O2 = fmaf(b12, mx0, fmaf(b22, mx1, fmaf(b32, mx2, u2)));
    };

    // two slices processed CONCURRENTLY (independent acc/s_load/GS chains)
    auto pair = [&](int sa, int sb,
                    float& A0, float& A1, float& A2,
                    float& B0, float& B1, float& B2) {
        const float* ta = tab + (size_t)sa * KK * ROW;  // uniform address
        const float* tb = tab + (size_t)sb * KK * ROW;  // uniform address

        f32x2 xa01 = {0.f,0.f}, xa23 = {0.f,0.f}, xa45 = {0.f,0.f}, xa67 = {0.f,0.f};
        f32x2 xb01 = {0.f,0.f}, xb23 = {0.f,0.f}, xb45 = {0.f,0.f}, xb67 = {0.f,0.f};
        float xa8 = 0.f, xb8 = 0.f;

        #pragma unroll
        for (int k = 0; k < KK; ++k) {
            const f32x2 wk = ((k & 1) == 0)
                ? (f32x2){w2[k>>1].x, w2[k>>1].x}
                : (f32x2){w2[k>>1].y, w2[k>>1].y};
            xa01 += wk * *reinterpret_cast<const f32x2*>(ta + k*ROW + 0);
            xa23 += wk * *reinterpret_cast<const f32x2*>(ta + k*ROW + 2);
            xa45 += wk * *reinterpret_cast<const f32x2*>(ta + k*ROW + 4);
            xa67 += wk * *reinterpret_cast<const f32x2*>(ta + k*ROW + 6);
            xa8   = fmaf(wk.x, ta[k*ROW + 8], xa8);
            xb01 += wk * *reinterpret_cast<const f32x2*>(tb + k*ROW + 0);
            xb23 += wk * *reinterpret_cast<const f32x2*>(tb + k*ROW + 2);
            xb45 += wk * *reinterpret_cast<const f32x2*>(tb + k*ROW + 4);
            xb67 += wk * *reinterpret_cast<const f32x2*>(tb + k*ROW + 6);
            xb8   = fmaf(wk.x, tb[k*ROW + 8], xb8);
        }

        finish(xa01.x, xa01.y, xa23.x, xa23.y, xa45.x, xa45.y,
               xa67.x, xa67.y, xa8, A0, A1, A2);
        finish(xb01.x, xb01.y, xb23.x, xb23.y, xb45.x, xb45.y,
               xb67.x, xb67.y, xb8, B0, B1, B2);
    };

    // 4 slices = 2 ILP-2 rounds; outputs named (compile-time, no scratch)
    float o0,o1,o2,o3,o4,o5,o6,o7,o8,o9,o10,o11;
    const int s0 = q4 * 4;
    pair(s0 + 0, s0 + 1, o0, o1, o2, o3,  o4,  o5);
    pair(s0 + 2, s0 + 3, o6, o7, o8, o9,  o10, o11);

    if (p < G) {
        // slices s0..s0+3 are 12 contiguous floats: byte 96p + 48*q4 (16-al.)
        float4* op = reinterpret_cast<float4*>(out + (size_t)p * (BB*3) + q4 * 12);
        op[0] = make_float4(o0, o1, o2,  o3);
        op[1] = make_float4(o4, o5, o6,  o7);
        op[2] = make_float4(o8, o9, o10, o11);
    }
}

extern "C" void kernel_launch(void* const* d_in, const int* in_sizes, int n_in,
                              void* d_out, int out_size, void* d_ws, size_t ws_size,
                              hipStream_t stream) {
    const float* motion_rots    = (const float*)d_in[0];
    const float* motion_transls = (const float*)d_in[1];
    const float* motion_coefs   = (const float*)d_in[2];
    const float* means          = (const float*)d_in[3];
    const int*   ts             = (const int*)d_in[4];
    float* out = (float*)d_out;
    float* tab = (float*)d_ws;   // needs BB*KK*ROW*4 = 7680 B

    const int G = in_sizes[3] / 3;            // means is (G,3)
    const int F = in_sizes[0] / (6 * KK);     // motion_rots is (K,F,6)

    gather_tab<<<1, 192, 0, stream>>>(motion_rots, motion_transls, ts, tab, F);

    const int nblk = (G + GPB - 1) / GPB;     // 128 gaussians per block
    motion_fwd<<<nblk, BLK, 0, stream>>>(motion_coefs, means, tab, out, G);
}